// Round 1
// baseline (3041.645 us; speedup 1.0000x reference)
//
#include <hip/hip_runtime.h>
#include <hip/hip_bf16.h>
#include <math.h>

// Problem constants
#define B_  2048
#define CV_ 128
#define E_  64
#define H_  512
#define T_  20

// Step-GEMM tiling: per block 64 rows x 64 cols (x3 gates), K chunks of 32.
#define BM 64
#define BN 64
#define KB 32
#define NTHREADS 256

__device__ __forceinline__ float sigmoidf_(float x) {
  return 1.0f / (1.0f + expf(-x));
}

// ---------------------------------------------------------------------------
// Setup: lengths, stable counting-sort perm (matches stable argsort(-len)),
// sorted lengths, and M_t = #(len > t) for t in [0,20).
// ---------------------------------------------------------------------------
__global__ void k_setup(const int* __restrict__ data, const int* __restrict__ st,
                        int* __restrict__ perm, int* __restrict__ slen,
                        int* __restrict__ Mt) {
  __shared__ int lens[B_];
  __shared__ int cnt[T_ + 1];
  __shared__ int offs[T_ + 1];
  int tid = threadIdx.x;
  if (tid <= T_) cnt[tid] = 0;
  __syncthreads();
  for (int i = tid; i < B_; i += NTHREADS) {
    int L = st[data[i] * (T_ + 1) + T_];
    lens[i] = L;
    atomicAdd(&cnt[L], 1);
  }
  __syncthreads();
  if (tid <= T_) {
    int s = 0;
    for (int L = tid + 1; L <= T_; ++L) s += cnt[L];
    offs[tid] = s;   // offs[x] = count of items with len > x
  }
  __syncthreads();
  if (tid < T_) Mt[tid] = offs[tid];
  if (tid >= 1 && tid <= T_) {
    // stable scatter: lengths descending, original index ascending within ties
    int pos = offs[tid];
    for (int i = 0; i < B_; ++i) {
      if (lens[i] == tid) { perm[pos] = i; slen[pos] = tid; ++pos; }
    }
  }
}

// ---------------------------------------------------------------------------
// Gather spelling chars in sorted-row order, transposed: schars_T[t][j]
// ---------------------------------------------------------------------------
__global__ void k_schars(const int* __restrict__ data, const int* __restrict__ st,
                         const int* __restrict__ perm, int* __restrict__ schars_T) {
  int idx = blockIdx.x * NTHREADS + threadIdx.x;
  if (idx >= B_ * T_) return;
  int t = idx >> 11;          // idx / 2048
  int j = idx & (B_ - 1);     // idx % 2048
  schars_T[idx] = st[data[perm[j]] * (T_ + 1) + t];
}

__global__ void k_zero(float* __restrict__ p, int n) {
  int i = blockIdx.x * NTHREADS + threadIdx.x;
  if (i < n) p[i] = 0.0f;
}

// ---------------------------------------------------------------------------
// One GRU time step, fused GEMM + gates.
//   A (M_t x 576) = [ emb[chars[:,t]] (64) | h_in (512) ]
//   W (1536 x 576) = [ W_ih | W_hh ]   (3 gates r,z,n)
// Block computes rows [m0,m0+64) x cols [n0,n0+64) of H for all 3 gates,
// then applies the GRU update and writes h_out.  n-gate x/h parts kept
// separate (n = tanh(xn + r*hn)).
// ---------------------------------------------------------------------------
__global__ __launch_bounds__(NTHREADS) void k_step(
    int t, const int* __restrict__ Mt, const int* __restrict__ schars_T,
    const float* __restrict__ emb, const float* __restrict__ W_ih,
    const float* __restrict__ W_hh, const float* __restrict__ b_ih,
    const float* __restrict__ b_hh, const float* __restrict__ h_in,
    float* __restrict__ h_out) {
  int M = Mt[t];
  int m0 = blockIdx.x * BM;
  if (m0 >= M) return;            // whole row-tile inactive this step
  int n0 = blockIdx.y * BN;

  __shared__ __attribute__((aligned(16))) float As[KB][BM + 4];       // [k][row]
  __shared__ __attribute__((aligned(16))) float Ws[KB][3 * BN + 4];   // [k][gate*64+col]
  __shared__ int chs[BM];

  int tid = threadIdx.x;
  int tx = tid & 15;        // col group: cols n0 + tx*4 .. +3
  int ty = tid >> 4;        // row group: rows m0 + ty*4 .. +3

  if (tid < BM) chs[tid] = schars_T[t * B_ + m0 + tid];

  float accr[4][4] = {};
  float accz[4][4] = {};
  float accnx[4][4] = {};
  float accnh[4][4] = {};

  const int NCHUNK = (E_ + H_) / KB;   // 18
  for (int c = 0; c < NCHUNK; ++c) {
    int kg0 = c * KB;
    __syncthreads();
    // ---- stage A chunk (KB x BM) ----
    #pragma unroll
    for (int q = tid; q < KB * BM; q += NTHREADS) {
      int k = q & (KB - 1);
      int jj = q >> 5;
      int kg = kg0 + k;
      float v;
      if (c < 2) {                       // x part: emb[char]
        v = emb[chs[jj] * E_ + kg];
      } else {                           // h part
        v = h_in[(m0 + jj) * H_ + (kg - E_)];
      }
      As[k][jj] = v;
    }
    // ---- stage W chunk (KB x 192) ----
    #pragma unroll
    for (int q = tid; q < KB * 3 * BN; q += NTHREADS) {
      int k = q & (KB - 1);
      int gg = q >> 5;
      int gate = gg >> 6;
      int col = gg & 63;
      int grow = gate * H_ + n0 + col;
      int kg = kg0 + k;
      float v;
      if (c < 2) v = W_ih[grow * E_ + kg];
      else       v = W_hh[grow * H_ + (kg - E_)];
      Ws[k][gg] = v;
    }
    __syncthreads();
    // ---- compute ----
    if (c < 2) {
      #pragma unroll
      for (int k = 0; k < KB; ++k) {
        float4 a  = *(const float4*)&As[k][ty * 4];
        float4 w0 = *(const float4*)&Ws[k][0 * BN + tx * 4];
        float4 w1 = *(const float4*)&Ws[k][1 * BN + tx * 4];
        float4 w2 = *(const float4*)&Ws[k][2 * BN + tx * 4];
        float av[4] = {a.x, a.y, a.z, a.w};
        float w0v[4] = {w0.x, w0.y, w0.z, w0.w};
        float w1v[4] = {w1.x, w1.y, w1.z, w1.w};
        float w2v[4] = {w2.x, w2.y, w2.z, w2.w};
        #pragma unroll
        for (int i = 0; i < 4; ++i)
          #pragma unroll
          for (int j = 0; j < 4; ++j) {
            accr[i][j]  = fmaf(av[i], w0v[j], accr[i][j]);
            accz[i][j]  = fmaf(av[i], w1v[j], accz[i][j]);
            accnx[i][j] = fmaf(av[i], w2v[j], accnx[i][j]);
          }
      }
    } else {
      #pragma unroll
      for (int k = 0; k < KB; ++k) {
        float4 a  = *(const float4*)&As[k][ty * 4];
        float4 w0 = *(const float4*)&Ws[k][0 * BN + tx * 4];
        float4 w1 = *(const float4*)&Ws[k][1 * BN + tx * 4];
        float4 w2 = *(const float4*)&Ws[k][2 * BN + tx * 4];
        float av[4] = {a.x, a.y, a.z, a.w};
        float w0v[4] = {w0.x, w0.y, w0.z, w0.w};
        float w1v[4] = {w1.x, w1.y, w1.z, w1.w};
        float w2v[4] = {w2.x, w2.y, w2.z, w2.w};
        #pragma unroll
        for (int i = 0; i < 4; ++i)
          #pragma unroll
          for (int j = 0; j < 4; ++j) {
            accr[i][j]  = fmaf(av[i], w0v[j], accr[i][j]);
            accz[i][j]  = fmaf(av[i], w1v[j], accz[i][j]);
            accnh[i][j] = fmaf(av[i], w2v[j], accnh[i][j]);
          }
      }
    }
  }

  // ---- epilogue: GRU gates + h update ----
  #pragma unroll
  for (int i = 0; i < 4; ++i) {
    int row = m0 + ty * 4 + i;
    if (row >= M) continue;                 // inactive row: keep state as-is
    int cbase = n0 + tx * 4;
    float4 hold4 = *(const float4*)&h_in[row * H_ + cbase];
    float holdv[4] = {hold4.x, hold4.y, hold4.z, hold4.w};
    float out4[4];
    #pragma unroll
    for (int j = 0; j < 4; ++j) {
      int col = cbase + j;
      float pr = accr[i][j] + b_ih[col] + b_hh[col];
      float pz = accz[i][j] + b_ih[H_ + col] + b_hh[H_ + col];
      float xn = accnx[i][j] + b_ih[2 * H_ + col];
      float hn = accnh[i][j] + b_hh[2 * H_ + col];
      float r = sigmoidf_(pr);
      float z = sigmoidf_(pz);
      float n = tanhf(xn + r * hn);
      out4[j] = (1.0f - z) * n + z * holdv[j];
    }
    float4 o4 = {out4[0], out4[1], out4[2], out4[3]};
    *(float4*)&h_out[row * H_ + cbase] = o4;
  }
}

// ---------------------------------------------------------------------------
// Final gather: out[i] = ht_sorted[perm[i]]  (reference returns ht[perm]).
// Row j's final h lives in buf[len&1] (step t reads buf[t&1], writes buf[~t&1]).
// ---------------------------------------------------------------------------
__global__ void k_gather(const float* __restrict__ buf0, const float* __restrict__ buf1,
                         const int* __restrict__ perm, const int* __restrict__ slen,
                         float* __restrict__ out) {
  int idx = blockIdx.x * NTHREADS + threadIdx.x;
  if (idx >= B_ * H_) return;
  int i = idx >> 9;          // / 512
  int c = idx & (H_ - 1);
  int j = perm[i];
  const float* src = (slen[j] & 1) ? buf1 : buf0;
  out[idx] = src[j * H_ + c];
}

extern "C" void kernel_launch(void* const* d_in, const int* in_sizes, int n_in,
                              void* d_out, int out_size, void* d_ws, size_t ws_size,
                              hipStream_t stream) {
  const int*   data = (const int*)d_in[0];
  const int*   st   = (const int*)d_in[1];   // spelling_table (V x 21)
  const float* emb  = (const float*)d_in[2];
  const float* W_ih = (const float*)d_in[3];
  const float* W_hh = (const float*)d_in[4];
  const float* b_ih = (const float*)d_in[5];
  const float* b_hh = (const float*)d_in[6];
  float* out = (float*)d_out;

  // workspace layout
  float* buf0 = (float*)d_ws;                  // B*H floats
  float* buf1 = buf0 + B_ * H_;                // B*H floats
  int* perm   = (int*)(buf1 + B_ * H_);        // B
  int* slen   = perm + B_;                     // B
  int* Mt     = slen + B_;                     // T (padded to 32)
  int* schars = Mt + 32;                       // T*B

  k_setup<<<1, NTHREADS, 0, stream>>>(data, st, perm, slen, Mt);
  k_schars<<<(B_ * T_ + NTHREADS - 1) / NTHREADS, NTHREADS, 0, stream>>>(data, st, perm, schars);
  k_zero<<<(B_ * H_ + NTHREADS - 1) / NTHREADS, NTHREADS, 0, stream>>>(buf0, B_ * H_);

  dim3 grid(B_ / BM, H_ / BN);   // 32 x 8
  for (int t = 0; t < T_; ++t) {
    const float* hin = (t & 1) ? buf1 : buf0;
    float*       hout = (t & 1) ? buf0 : buf1;
    k_step<<<grid, NTHREADS, 0, stream>>>(t, Mt, schars, emb, W_ih, W_hh,
                                          b_ih, b_hh, hin, hout);
  }

  k_gather<<<(B_ * H_ + NTHREADS - 1) / NTHREADS, NTHREADS, 0, stream>>>(
      buf0, buf1, perm, slen, out);
}

// Round 2
// 752.780 us; speedup vs baseline: 4.0405x; 4.0405x over previous
//
#include <hip/hip_runtime.h>
#include <hip/hip_bf16.h>
#include <math.h>

#define B_  2048
#define E_  64
#define H_  512
#define T_  20
#define GK  576          // E + H
#define NG  1536         // 3*H
#define NTHREADS 256

typedef __attribute__((ext_vector_type(8))) short short8;
typedef __attribute__((ext_vector_type(4))) float f32x4;

__device__ __forceinline__ unsigned short f2bf(float f) {
  unsigned u = __float_as_uint(f);
  u += 0x7fffu + ((u >> 16) & 1u);
  return (unsigned short)(u >> 16);
}
__device__ __forceinline__ float bf2f(unsigned short s) {
  return __uint_as_float(((unsigned)s) << 16);
}
__device__ __forceinline__ float sigmoidf_(float x) {
  return 1.0f / (1.0f + __expf(-x));
}
__device__ __forceinline__ float tanh_fast(float x) {
  float e = __expf(2.0f * x);
  return 1.0f - 2.0f / (e + 1.0f);
}

// ---------------------------------------------------------------------------
// Setup: stable counting-sort perm (matches stable argsort(-len)), sorted
// lengths, and M_t = #(len > t).
// ---------------------------------------------------------------------------
__global__ void k_setup(const int* __restrict__ data, const int* __restrict__ st,
                        int* __restrict__ perm, int* __restrict__ slen,
                        int* __restrict__ Mt) {
  __shared__ int lens[B_];
  __shared__ int cnt[T_ + 1];
  __shared__ int offs[T_ + 1];
  int tid = threadIdx.x;
  if (tid <= T_) cnt[tid] = 0;
  __syncthreads();
  for (int i = tid; i < B_; i += NTHREADS) {
    int L = st[data[i] * (T_ + 1) + T_];
    lens[i] = L;
    atomicAdd(&cnt[L], 1);
  }
  __syncthreads();
  if (tid <= T_) {
    int s = 0;
    for (int L = tid + 1; L <= T_; ++L) s += cnt[L];
    offs[tid] = s;   // offs[x] = count of items with len > x
  }
  __syncthreads();
  if (tid < T_) Mt[tid] = offs[tid];
  if (tid >= 1 && tid <= T_) {
    int pos = offs[tid];
    for (int i = 0; i < B_; ++i) {
      if (lens[i] == tid) { perm[pos] = i; slen[pos] = tid; ++pos; }
    }
  }
}

__global__ void k_schars(const int* __restrict__ data, const int* __restrict__ st,
                         const int* __restrict__ perm, int* __restrict__ schars_T) {
  int idx = blockIdx.x * NTHREADS + threadIdx.x;
  if (idx >= B_ * T_) return;
  int t = idx >> 11;
  int j = idx & (B_ - 1);
  schars_T[idx] = st[data[perm[j]] * (T_ + 1) + t];
}

__global__ void k_zero(float* __restrict__ p, int n) {
  int i = blockIdx.x * NTHREADS + threadIdx.x;
  if (i < n) p[i] = 0.0f;
}

// W (fp32, [g][k] with k = [E | H]) -> bf16 hi/lo, same [g][k] layout.
__global__ void k_wconv(const float* __restrict__ W_ih, const float* __restrict__ W_hh,
                        short* __restrict__ Wbh, short* __restrict__ Wbl) {
  int g = blockIdx.x;
  for (int k = threadIdx.x; k < GK; k += NTHREADS) {
    float wv = (k < E_) ? W_ih[g * E_ + k] : W_hh[g * H_ + (k - E_)];
    unsigned short hi = f2bf(wv);
    float lo = wv - bf2f(hi);
    Wbh[g * GK + k] = (short)hi;
    Wbl[g * GK + k] = (short)f2bf(lo);
  }
}

__global__ void k_embconv(const float* __restrict__ emb,
                          short* __restrict__ ebh, short* __restrict__ ebl) {
  int idx = blockIdx.x * NTHREADS + threadIdx.x;
  if (idx >= 128 * E_) return;
  float v = emb[idx];
  unsigned short hi = f2bf(v);
  ebh[idx] = (short)hi;
  ebl[idx] = (short)f2bf(v - bf2f(hi));
}

// ---------------------------------------------------------------------------
// One GRU step. Block: 64 rows x (3 gates x 64 cols). 4 waves, wave w owns
// rows [w*16, w*16+16). MFMA 16x16x32 bf16, split-bf16 3-pass for accuracy.
// acc frags: 0-3 = r, 4-7 = z, 8-11 = n(x-part), 12-15 = n(h-part).
// ---------------------------------------------------------------------------
__global__ __launch_bounds__(NTHREADS) void k_step(
    int t, const int* __restrict__ Mt, const int* __restrict__ schars_T,
    const short* __restrict__ ebh, const short* __restrict__ ebl,
    const short* __restrict__ Wbh, const short* __restrict__ Wbl,
    const float* __restrict__ b_ih, const float* __restrict__ b_hh,
    const short* __restrict__ rdh, const short* __restrict__ rdl,
    short* __restrict__ wrh, short* __restrict__ wrl,
    float* __restrict__ hf) {
  int M = Mt[t];
  int m0 = blockIdx.x * 64;
  if (m0 >= M) return;
  int n0 = blockIdx.y * 64;

  __shared__ __attribute__((aligned(16))) short As[2][64][40];   // [part][row][k]
  __shared__ __attribute__((aligned(16))) short Ws[2][192][40];  // [part][blockcol][k]
  __shared__ int chs[64];

  int tid = threadIdx.x;
  int w = tid >> 6;
  int l = tid & 63;
  int ln = l & 15;
  int kc = l >> 4;

  if (tid < 64) chs[tid] = schars_T[t * B_ + m0 + tid];

  f32x4 acc[16];
  #pragma unroll
  for (int i = 0; i < 16; ++i) acc[i] = (f32x4){0.f, 0.f, 0.f, 0.f};

  for (int c = 0; c < 18; ++c) {
    int k0 = c * 32;
    __syncthreads();
    // ---- stage A chunk: 64 rows x 32 k, hi+lo ----
    #pragma unroll
    for (int q = 0; q < 2; ++q) {
      int idx = tid + 256 * q;
      int part = idx >> 8;
      int rem = idx & 255;
      int r = rem >> 2;
      int c4 = rem & 3;
      const short* src;
      if (c < 2) {
        const short* base = part ? ebl : ebh;
        src = base + chs[r] * E_ + k0 + c4 * 8;
      } else {
        const short* base = part ? rdl : rdh;
        src = base + (m0 + r) * H_ + (k0 - E_) + c4 * 8;
      }
      *(short8*)&As[part][r][c4 * 8] = *(const short8*)src;
    }
    // ---- stage W chunk: 192 gate-cols x 32 k, hi+lo ----
    #pragma unroll
    for (int q = 0; q < 6; ++q) {
      int idx = tid + 256 * q;
      int part = (idx >= 768) ? 1 : 0;
      int rem = idx - part * 768;
      int bc = rem >> 2;
      int c4 = rem & 3;
      int g = ((bc >> 6) << 9) + n0 + (bc & 63);
      const short* base = part ? Wbl : Wbh;
      const short* src = base + g * GK + k0 + c4 * 8;
      *(short8*)&Ws[part][bc][c4 * 8] = *(const short8*)src;
    }
    __syncthreads();

    short8 ah = *(const short8*)&As[0][w * 16 + ln][kc * 8];
    short8 al = *(const short8*)&As[1][w * 16 + ln][kc * 8];
    if (c < 2) {
      #pragma unroll
      for (int f = 0; f < 12; ++f) {
        short8 wh8 = *(const short8*)&Ws[0][f * 16 + ln][kc * 8];
        short8 wl8 = *(const short8*)&Ws[1][f * 16 + ln][kc * 8];
        acc[f] = __builtin_amdgcn_mfma_f32_16x16x32_bf16(ah, wh8, acc[f], 0, 0, 0);
        acc[f] = __builtin_amdgcn_mfma_f32_16x16x32_bf16(al, wh8, acc[f], 0, 0, 0);
        acc[f] = __builtin_amdgcn_mfma_f32_16x16x32_bf16(ah, wl8, acc[f], 0, 0, 0);
      }
    } else {
      #pragma unroll
      for (int f = 0; f < 12; ++f) {
        short8 wh8 = *(const short8*)&Ws[0][f * 16 + ln][kc * 8];
        short8 wl8 = *(const short8*)&Ws[1][f * 16 + ln][kc * 8];
        int ai = (f < 8) ? f : f + 4;   // n-gate h-part -> acc 12..15
        acc[ai] = __builtin_amdgcn_mfma_f32_16x16x32_bf16(ah, wh8, acc[ai], 0, 0, 0);
        acc[ai] = __builtin_amdgcn_mfma_f32_16x16x32_bf16(al, wh8, acc[ai], 0, 0, 0);
        acc[ai] = __builtin_amdgcn_mfma_f32_16x16x32_bf16(ah, wl8, acc[ai], 0, 0, 0);
      }
    }
  }

  // ---- epilogue: GRU gates, fp32 h update, bf16 hi/lo h for next step ----
  int row_l = w * 16 + kc * 4;
  #pragma unroll
  for (int cq = 0; cq < 4; ++cq) {
    int cn = n0 + cq * 16 + ln;
    float br  = b_ih[cn] + b_hh[cn];
    float bz  = b_ih[H_ + cn] + b_hh[H_ + cn];
    float bnx = b_ih[2 * H_ + cn];
    float bnh = b_hh[2 * H_ + cn];
    #pragma unroll
    for (int q = 0; q < 4; ++q) {
      int row = m0 + row_l + q;
      if (row >= M) continue;
      float pr = acc[cq][q] + br;
      float pz = acc[4 + cq][q] + bz;
      float xn = acc[8 + cq][q] + bnx;
      float hn = acc[12 + cq][q] + bnh;
      float r = sigmoidf_(pr);
      float z = sigmoidf_(pz);
      float n = tanh_fast(xn + r * hn);
      float hold = hf[row * H_ + cn];
      float hnew = (1.0f - z) * n + z * hold;
      hf[row * H_ + cn] = hnew;
      unsigned short hb = f2bf(hnew);
      wrh[row * H_ + cn] = (short)hb;
      wrl[row * H_ + cn] = (short)f2bf(hnew - bf2f(hb));
    }
  }
}

__global__ void k_gather(const float* __restrict__ hf, const int* __restrict__ perm,
                         float* __restrict__ out) {
  int idx = blockIdx.x * NTHREADS + threadIdx.x;
  if (idx >= B_ * H_) return;
  int i = idx >> 9;
  int cc = idx & (H_ - 1);
  out[idx] = hf[perm[i] * H_ + cc];
}

extern "C" void kernel_launch(void* const* d_in, const int* in_sizes, int n_in,
                              void* d_out, int out_size, void* d_ws, size_t ws_size,
                              hipStream_t stream) {
  const int*   data = (const int*)d_in[0];
  const int*   st   = (const int*)d_in[1];
  const float* emb  = (const float*)d_in[2];
  const float* W_ih = (const float*)d_in[3];
  const float* W_hh = (const float*)d_in[4];
  const float* b_ih = (const float*)d_in[5];
  const float* b_hh = (const float*)d_in[6];
  float* out = (float*)d_out;

  // workspace layout (~16.3 MB)
  float* hf   = (float*)d_ws;                 // B*H fp32
  short* hbAh = (short*)(hf + B_ * H_);       // B*H bf16 each
  short* hbAl = hbAh + B_ * H_;
  short* hbBh = hbAl + B_ * H_;
  short* hbBl = hbBh + B_ * H_;
  short* Wbh  = hbBl + B_ * H_;               // NG*GK
  short* Wbl  = Wbh + NG * GK;
  short* ebh  = Wbl + NG * GK;                // 128*E
  short* ebl  = ebh + 128 * E_;
  int* perm   = (int*)(ebl + 128 * E_);
  int* slen   = perm + B_;
  int* Mt     = slen + B_;
  int* schars = Mt + 32;

  k_setup<<<1, NTHREADS, 0, stream>>>(data, st, perm, slen, Mt);
  k_schars<<<(B_ * T_ + NTHREADS - 1) / NTHREADS, NTHREADS, 0, stream>>>(data, st, perm, schars);
  k_zero<<<(B_ * H_ + NTHREADS - 1) / NTHREADS, NTHREADS, 0, stream>>>(hf, B_ * H_);
  // hbAh + hbAl are contiguous: 2*B*H shorts == B*H floats
  k_zero<<<(B_ * H_ + NTHREADS - 1) / NTHREADS, NTHREADS, 0, stream>>>((float*)hbAh, B_ * H_);
  k_wconv<<<NG, NTHREADS, 0, stream>>>(W_ih, W_hh, Wbh, Wbl);
  k_embconv<<<(128 * E_ + NTHREADS - 1) / NTHREADS, NTHREADS, 0, stream>>>(emb, ebh, ebl);

  dim3 grid(B_ / 64, 8);
  for (int t = 0; t < T_; ++t) {
    const short* rh = (t & 1) ? hbBh : hbAh;
    const short* rl = (t & 1) ? hbBl : hbAl;
    short* wh = (t & 1) ? hbAh : hbBh;
    short* wl = (t & 1) ? hbAl : hbBl;
    k_step<<<grid, NTHREADS, 0, stream>>>(t, Mt, schars, ebh, ebl, Wbh, Wbl,
                                          b_ih, b_hh, rh, rl, wh, wl, hf);
  }

  k_gather<<<(B_ * H_ + NTHREADS - 1) / NTHREADS, NTHREADS, 0, stream>>>(hf, perm, out);
}